// Round 8
// baseline (697.201 us; speedup 1.0000x reference)
//
#include <hip/hip_runtime.h>
#include <hip/hip_cooperative_groups.h>
#include <math.h>

namespace cg = cooperative_groups;

#define D_FEAT 32
#define BSHIFT 5                 // 32 nodes per bucket
#define NPB 32                   // nodes per bucket
#define TILE 8192
#define PT 32                    // edges per thread in hist/partition (TILE/256)
#define MAXBKT 2048              // >= 1563, pow2
#define CAP 2048                 // bucket capacity (mean 1024, +32 sigma)
#define GRID 1024
#define BLK 256

// Phase-overlaid LDS (max ~16.5 KB -> 4 blocks/CU fits in 160 KB)
union SmemU {
    int hist[MAXBKT];                                   // phase B
    int scan[BLK];                                      // phase C
    struct { int h[MAXBKT]; int baseL[MAXBKT]; } p;     // phase D
    struct {
        unsigned int ukey[CAP];
        int seid[CAP];
        int nh[NPB];
        int noff[NPB + 1];
        int ncur[NPB];
    } g;                                                // phase E
};

__global__ __launch_bounds__(BLK, 4) void fused_kernel(
        const float* __restrict__ m,
        const int* __restrict__ dst,
        const float* __restrict__ w,
        const float* __restrict__ bia,
        float* __restrict__ out,
        int* __restrict__ bucketCount,
        int* __restrict__ bucketBase,
        int* __restrict__ bucketCursor,
        unsigned int* __restrict__ keys,
        int E, int N, int nbucket, int nTiles) {
    cg::grid_group grid = cg::this_grid();
    __shared__ SmemU S;
    const int tid = threadIdx.x;
    const int bid = blockIdx.x;
    const int E4 = E >> 2;
    const int4* dst4 = (const int4*)dst;

    // ---------- Phase A: zero bucket counters (replaces host memset) ----------
    for (int i = bid * BLK + tid; i < MAXBKT; i += GRID * BLK) bucketCount[i] = 0;
    grid.sync();

    // ---------- Phase B: bucket histogram (LDS-aggregated, int4 loads) ----------
    if (bid < nTiles) {
        for (int i = tid; i < MAXBKT; i += BLK) S.hist[i] = 0;
        __syncthreads();
        int tbase4 = bid * (TILE / 4);
        #pragma unroll
        for (int k = 0; k < PT / 4; k++) {
            int i4 = tbase4 + k * BLK + tid;
            if (i4 < E4) {
                int4 d = dst4[i4];
                atomicAdd(&S.hist[d.x >> BSHIFT], 1);
                atomicAdd(&S.hist[d.y >> BSHIFT], 1);
                atomicAdd(&S.hist[d.z >> BSHIFT], 1);
                atomicAdd(&S.hist[d.w >> BSHIFT], 1);
            }
        }
        __syncthreads();
        for (int i = tid; i < nbucket; i += BLK) {
            int c = S.hist[i];
            if (c) atomicAdd(&bucketCount[i], c);
        }
    }
    grid.sync();

    // ---------- Phase C: scan bucket counts -> bases + cursors (block 0) ----------
    if (bid == 0) {
        int vals[8];
        int s = 0;
        #pragma unroll
        for (int k = 0; k < 8; k++) {
            int i = tid * 8 + k;
            vals[k] = (i < nbucket) ? bucketCount[i] : 0;
            s += vals[k];
        }
        S.scan[tid] = s;
        __syncthreads();
        for (int off = 1; off < BLK; off <<= 1) {
            int t = (tid >= off) ? S.scan[tid - off] : 0;
            __syncthreads();
            S.scan[tid] += t;
            __syncthreads();
        }
        int run = S.scan[tid] - s;     // exclusive prefix
        #pragma unroll
        for (int k = 0; k < 8; k++) {
            int i = tid * 8 + k;
            if (i < nbucket) { bucketBase[i] = run; bucketCursor[i] = run; }
            run += vals[k];
        }
        if (tid == 0) bucketBase[nbucket] = E;
    }
    grid.sync();

    // ---------- Phase D: partition edges into buckets (packed keys) ----------
    // pk = (b << 18) | (localnode << 13) | rank ; key = localnode << 26 | eid
    if (bid < nTiles) {
        for (int i = tid; i < MAXBKT; i += BLK) S.p.h[i] = 0;
        __syncthreads();
        int tbase4 = bid * (TILE / 4);
        int pk[PT];
        #pragma unroll
        for (int k = 0; k < PT / 4; k++) {
            int i4 = tbase4 + k * BLK + tid;
            if (i4 < E4) {
                int4 d = dst4[i4];
                int b0 = d.x >> BSHIFT; int r0 = atomicAdd(&S.p.h[b0], 1);
                int b1 = d.y >> BSHIFT; int r1 = atomicAdd(&S.p.h[b1], 1);
                int b2 = d.z >> BSHIFT; int r2 = atomicAdd(&S.p.h[b2], 1);
                int b3 = d.w >> BSHIFT; int r3 = atomicAdd(&S.p.h[b3], 1);
                pk[4 * k + 0] = (b0 << 18) | ((d.x & (NPB - 1)) << 13) | r0;
                pk[4 * k + 1] = (b1 << 18) | ((d.y & (NPB - 1)) << 13) | r1;
                pk[4 * k + 2] = (b2 << 18) | ((d.z & (NPB - 1)) << 13) | r2;
                pk[4 * k + 3] = (b3 << 18) | ((d.w & (NPB - 1)) << 13) | r3;
            } else {
                pk[4 * k + 0] = -1; pk[4 * k + 1] = -1;
                pk[4 * k + 2] = -1; pk[4 * k + 3] = -1;
            }
        }
        __syncthreads();
        for (int i = tid; i < nbucket; i += BLK) {
            int c = S.p.h[i];
            S.p.baseL[i] = c ? atomicAdd(&bucketCursor[i], c) : 0;
        }
        __syncthreads();
        #pragma unroll
        for (int k = 0; k < PT / 4; k++) {
            int i4 = tbase4 + k * BLK + tid;
            int e = i4 * 4;
            #pragma unroll
            for (int l = 0; l < 4; l++) {
                int p = pk[4 * k + l];
                if (p >= 0) {
                    int b   = p >> 18;
                    int loc = (p >> 13) & (NPB - 1);
                    int r   = p & 8191;
                    keys[S.p.baseL[b] + r] = ((unsigned)loc << 26) | (unsigned)(e + l);
                }
            }
        }
    }
    grid.sync();

    // ---------- Phase E: LDS counting-sort + float4 group gather ----------
    const float w0 = w[0], w1 = w[1], w2 = w[2], w3 = w[3], bb = bia[0];
    const int fo  = tid & 7;          // features 4*fo .. 4*fo+3
    const int grp = tid >> 3;         // 0..31: node group

    for (int bkt = bid; bkt < nbucket; bkt += GRID) {
        __syncthreads();              // protect LDS reuse across iterations/phases
        int start = bucketBase[bkt];
        int cnt = bucketBase[bkt + 1] - start;
        if (cnt > CAP) cnt = CAP;     // statistically impossible; OOB guard

        if (tid < NPB) S.g.nh[tid] = 0;
        __syncthreads();
        for (int i = tid; i < cnt; i += BLK) {
            unsigned int k = keys[start + i];   // single global read of keys
            S.g.ukey[i] = k;
            atomicAdd(&S.g.nh[k >> 26], 1);
        }
        __syncthreads();
        if (tid < NPB) {              // lanes 0..31 of wave 0: scan
            int v = S.g.nh[tid];
            int x = v;
            #pragma unroll
            for (int off = 1; off < NPB; off <<= 1) {
                int t = __shfl_up(x, off, 64);
                if (tid >= off) x += t;
            }
            S.g.noff[tid + 1] = x;
            if (tid == 0) S.g.noff[0] = 0;
            S.g.ncur[tid] = x - v;    // exclusive
        }
        __syncthreads();
        for (int i = tid; i < cnt; i += BLK) {
            unsigned int k = S.g.ukey[i];
            int pos = atomicAdd(&S.g.ncur[k >> 26], 1);
            S.g.seid[pos] = (int)(k & 0x03FFFFFFu);
        }
        __syncthreads();

        // gather: group grp owns node (bkt*32 + grp); one wave load = 8 rows
        const int node = (bkt << BSHIFT) + grp;
        const int s0 = S.g.noff[grp];
        const int e0 = S.g.noff[grp + 1];
        const int deg = e0 - s0;

        float sa0 = 0.f, sa1 = 0.f, sa2 = 0.f, sa3 = 0.f;
        float mn0 = INFINITY, mn1 = INFINITY, mn2 = INFINITY, mn3 = INFINITY;
        float mx0 = -INFINITY, mx1 = -INFINITY, mx2 = -INFINITY, mx3 = -INFINITY;

#define ACC(v)                                              \
        sa0 += (v).x; mn0 = fminf(mn0, (v).x); mx0 = fmaxf(mx0, (v).x); \
        sa1 += (v).y; mn1 = fminf(mn1, (v).y); mx1 = fmaxf(mx1, (v).y); \
        sa2 += (v).z; mn2 = fminf(mn2, (v).z); mx2 = fmaxf(mx2, (v).z); \
        sa3 += (v).w; mn3 = fminf(mn3, (v).w); mx3 = fmaxf(mx3, (v).w);

        int j = s0;
        for (; j + 4 <= e0; j += 4) {
            int ea = S.g.seid[j], eb = S.g.seid[j + 1];
            int ec = S.g.seid[j + 2], ed = S.g.seid[j + 3];
            float4 va = *(const float4*)&m[ea * D_FEAT + (fo << 2)];
            float4 vb = *(const float4*)&m[eb * D_FEAT + (fo << 2)];
            float4 vc = *(const float4*)&m[ec * D_FEAT + (fo << 2)];
            float4 vd = *(const float4*)&m[ed * D_FEAT + (fo << 2)];
            ACC(va); ACC(vb); ACC(vc); ACC(vd);
        }
        for (; j < e0; j++) {
            float4 v = *(const float4*)&m[S.g.seid[j] * D_FEAT + (fo << 2)];
            ACC(v);
        }
#undef ACC

        if (node < N) {
            bool has = deg > 0;
            float inv = 1.0f / fmaxf((float)deg, 1.0f);
            float4 o;
            o.x = w0 * sa0 + w1 * (has ? mn0 : 0.f) + w2 * (has ? mx0 : 0.f) + w3 * (sa0 * inv) + bb;
            o.y = w0 * sa1 + w1 * (has ? mn1 : 0.f) + w2 * (has ? mx1 : 0.f) + w3 * (sa1 * inv) + bb;
            o.z = w0 * sa2 + w1 * (has ? mn2 : 0.f) + w2 * (has ? mx2 : 0.f) + w3 * (sa2 * inv) + bb;
            o.w = w0 * sa3 + w1 * (has ? mn3 : 0.f) + w2 * (has ? mx3 : 0.f) + w3 * (sa3 * inv) + bb;
            *(float4*)&out[node * D_FEAT + (fo << 2)] = o;
        }
    }
}

extern "C" void kernel_launch(void* const* d_in, const int* in_sizes, int n_in,
                              void* d_out, int out_size, void* d_ws, size_t ws_size,
                              hipStream_t stream) {
    const float* m   = (const float*)d_in[0];
    const int*   dst = (const int*)  d_in[1];
    const float* w   = (const float*)d_in[2];
    const float* b   = (const float*)d_in[3];
    float* outp = (float*)d_out;

    int E = in_sizes[0] / D_FEAT;           // 1,600,000
    int N = out_size    / D_FEAT;           // 50,000
    int nbucket = (N + NPB - 1) >> BSHIFT;  // 1563
    int nTiles = (E + TILE - 1) / TILE;     // 196

    int* ws           = (int*)d_ws;
    int* bucketCount  = ws;                             // MAXBKT
    int* bucketBase   = bucketCount + MAXBKT;           // MAXBKT+1
    int* bucketCursor = bucketBase + MAXBKT + 1;        // MAXBKT
    unsigned int* keys = (unsigned int*)(bucketCursor + MAXBKT);   // E

    void* args[] = {
        (void*)&m, (void*)&dst, (void*)&w, (void*)&b, (void*)&outp,
        (void*)&bucketCount, (void*)&bucketBase, (void*)&bucketCursor,
        (void*)&keys, (void*)&E, (void*)&N, (void*)&nbucket, (void*)&nTiles
    };
    hipLaunchCooperativeKernel((void*)fused_kernel, dim3(GRID), dim3(BLK),
                               args, 0, stream);
}

// Round 9
// 343.895 us; speedup vs baseline: 2.0274x; 2.0274x over previous
//
#include <hip/hip_runtime.h>
#include <math.h>

#define D_FEAT 32
#define BSHIFT 7                 // 128 nodes per bucket
#define NPB 128                  // nodes per bucket
#define TILE 8192
#define PT 32                    // edges per thread in hist/partition (TILE/256)
#define MAXBKT 512               // row stride, pow2 >= nbucket=391
#define CAPG 5120                // gather stage capacity (mean 4092, +16 sigma)
#define GBLK 512                 // gather block threads

// ---------------- K1: per-tile histogram -> plain-store row (no atomics, no memset) ----------------
__global__ __launch_bounds__(256) void hist_kernel(const int* __restrict__ dst,
                                                   int* __restrict__ tileCnt, int E4) {
    __shared__ int h[MAXBKT];
    for (int i = threadIdx.x; i < MAXBKT; i += 256) h[i] = 0;
    __syncthreads();
    const int4* dst4 = (const int4*)dst;
    int tbase4 = blockIdx.x * (TILE / 4);
    #pragma unroll
    for (int k = 0; k < PT / 4; k++) {
        int i4 = tbase4 + k * 256 + threadIdx.x;
        if (i4 < E4) {
            int4 d = dst4[i4];
            atomicAdd(&h[d.x >> BSHIFT], 1);
            atomicAdd(&h[d.y >> BSHIFT], 1);
            atomicAdd(&h[d.z >> BSHIFT], 1);
            atomicAdd(&h[d.w >> BSHIFT], 1);
        }
    }
    __syncthreads();
    int t = blockIdx.x;
    for (int i = threadIdx.x; i < MAXBKT; i += 256)
        tileCnt[t * MAXBKT + i] = h[i];          // full row incl. zeros
}

// ---------------- K2: one block: bucket totals -> bases; per-tile scatter bases ----------------
// thread b owns bucket b; all tileCnt loads are coalesced across b.
__global__ __launch_bounds__(512) void scan_kernel(const int* __restrict__ tileCnt,
                                                   int* __restrict__ tileBase,
                                                   int* __restrict__ bucketBase,
                                                   int nTiles) {
    __shared__ int lds[512];
    int b = threadIdx.x;
    int total = 0;
    int t = 0;
    #pragma unroll 4
    for (; t + 4 <= nTiles; t += 4) {
        int c0 = tileCnt[(t + 0) * MAXBKT + b];
        int c1 = tileCnt[(t + 1) * MAXBKT + b];
        int c2 = tileCnt[(t + 2) * MAXBKT + b];
        int c3 = tileCnt[(t + 3) * MAXBKT + b];
        total += c0 + c1 + c2 + c3;
    }
    for (; t < nTiles; t++) total += tileCnt[t * MAXBKT + b];
    lds[b] = total;
    __syncthreads();
    for (int off = 1; off < 512; off <<= 1) {
        int v = (b >= off) ? lds[b - off] : 0;
        __syncthreads();
        lds[b] += v;
        __syncthreads();
    }
    int base = lds[b] - total;                   // exclusive prefix
    bucketBase[b] = base;                        // b >= nbucket: base == E (counts 0)
    if (b == 511) bucketBase[512] = lds[511];    // == E
    int run = base;
    for (t = 0; t < nTiles; t++) {
        tileBase[t * MAXBKT + b] = run;
        run += tileCnt[t * MAXBKT + b];
    }
}

// ---------------- K3: partition, deterministic bases (no cursor atomics) ----------------
// key = (local_node << 21) | eid   (local<128, eid<2^21)
__global__ __launch_bounds__(256) void partition_kernel(const int* __restrict__ dst,
                                                        const int* __restrict__ tileCnt,
                                                        const int* __restrict__ tileBase,
                                                        unsigned int* __restrict__ keys,
                                                        int E4, int nbucket) {
    __shared__ int h[MAXBKT];              // stage cursors (from local offsets)
    __shared__ int hoff[MAXBKT + 1];       // local exclusive offsets
    __shared__ int gbase[MAXBKT];          // deterministic global bases for this tile
    __shared__ int scanb[256];
    __shared__ unsigned int stage[TILE];
    int tid = threadIdx.x;
    int t = blockIdx.x;
    // load this tile's counts (computed by K1) + global bases (computed by K2)
    for (int i = tid; i < MAXBKT; i += 256) {
        h[i] = tileCnt[t * MAXBKT + i];
        gbase[i] = tileBase[t * MAXBKT + i];
    }
    __syncthreads();
    // local scan (2 bins per thread) -> hoff
    int v0 = h[2 * tid], v1 = h[2 * tid + 1];
    int s = v0 + v1;
    scanb[tid] = s;
    __syncthreads();
    for (int off = 1; off < 256; off <<= 1) {
        int tt = (tid >= off) ? scanb[tid - off] : 0;
        __syncthreads();
        scanb[tid] += tt;
        __syncthreads();
    }
    int run = scanb[tid] - s;
    hoff[2 * tid] = run;
    hoff[2 * tid + 1] = run + v0;
    if (tid == 255) hoff[MAXBKT] = run + s;
    __syncthreads();
    // reset h to local offsets (stage cursors)
    for (int i = tid; i < MAXBKT; i += 256) h[i] = hoff[i];
    __syncthreads();
    // rank + scatter packed keys into LDS stage
    const int4* dst4 = (const int4*)dst;
    int tbase4 = t * (TILE / 4);
    #pragma unroll
    for (int k = 0; k < PT / 4; k++) {
        int i4 = tbase4 + k * 256 + tid;
        if (i4 < E4) {
            int4 d = dst4[i4];
            int e = i4 * 4;
            int r;
            r = atomicAdd(&h[d.x >> BSHIFT], 1);
            stage[r] = ((unsigned)(d.x & (NPB - 1)) << 21) | (unsigned)e;
            r = atomicAdd(&h[d.y >> BSHIFT], 1);
            stage[r] = ((unsigned)(d.y & (NPB - 1)) << 21) | (unsigned)(e + 1);
            r = atomicAdd(&h[d.z >> BSHIFT], 1);
            stage[r] = ((unsigned)(d.z & (NPB - 1)) << 21) | (unsigned)(e + 2);
            r = atomicAdd(&h[d.w >> BSHIFT], 1);
            stage[r] = ((unsigned)(d.w & (NPB - 1)) << 21) | (unsigned)(e + 3);
        }
    }
    __syncthreads();
    // writeout: per-bucket contiguous runs at deterministic global bases
    for (int i = tid; i < nbucket; i += 256) {
        int lo = hoff[i], hi = hoff[i + 1];
        int g = gbase[i];
        for (int j = lo; j < hi; j++) keys[g + (j - lo)] = stage[j];
    }
}

// ---------------- K4: LDS counting-sort (128 bins) + float4 group gather ----------------
__global__ __launch_bounds__(GBLK) void bucket_gather_kernel(
        const float* __restrict__ m,
        const unsigned int* __restrict__ keys,
        const int* __restrict__ bucketBase,
        const float* __restrict__ w,
        const float* __restrict__ bia,
        float* __restrict__ out, int N) {
    __shared__ int seid[CAPG];
    __shared__ int nh[NPB];
    __shared__ int noff[NPB + 1];
    __shared__ int ncur[NPB];
    int bkt = blockIdx.x;
    int tid = threadIdx.x;
    int start = bucketBase[bkt];
    int cnt = bucketBase[bkt + 1] - start;
    if (cnt > CAPG) cnt = CAPG;          // statistically impossible; OOB guard

    for (int i = tid; i < NPB; i += GBLK) nh[i] = 0;
    __syncthreads();
    for (int i = tid; i < cnt; i += GBLK)
        atomicAdd(&nh[keys[start + i] >> 21], 1);
    __syncthreads();
    if (tid < 64) {                       // wave 0: scan 128 bins, 2 per lane
        int a0 = nh[2 * tid], a1 = nh[2 * tid + 1];
        int s = a0 + a1;
        int x = s;
        #pragma unroll
        for (int off = 1; off < 64; off <<= 1) {
            int t = __shfl_up(x, off, 64);
            if (tid >= off) x += t;
        }
        int base = x - s;                 // exclusive
        noff[2 * tid] = base;      ncur[2 * tid] = base;
        noff[2 * tid + 1] = base + a0; ncur[2 * tid + 1] = base + a0;
        if (tid == 63) noff[NPB] = x;
    }
    __syncthreads();
    for (int i = tid; i < cnt; i += GBLK) {
        unsigned int k = keys[start + i];   // L2-warm second read
        int pos = atomicAdd(&ncur[k >> 21], 1);
        seid[pos] = (int)(k & 0x1FFFFFu);
    }
    __syncthreads();

    // gather: 8-lane group per node; fo = float4 feature chunk; 8 rows per wave load
    const int fo  = tid & 7;
    const int grp = tid >> 3;             // 0..63
    const float w0 = w[0], w1 = w[1], w2 = w[2], w3 = w[3], bb = bia[0];

    for (int nl = grp; nl < NPB; nl += 64) {
        int node = (bkt << BSHIFT) + nl;
        if (node >= N) break;
        int s0 = noff[nl];     if (s0 > cnt) s0 = cnt;
        int e0 = noff[nl + 1]; if (e0 > cnt) e0 = cnt;
        int deg = e0 - s0;
        float sa0 = 0.f, sa1 = 0.f, sa2 = 0.f, sa3 = 0.f;
        float mn0 = INFINITY, mn1 = INFINITY, mn2 = INFINITY, mn3 = INFINITY;
        float mx0 = -INFINITY, mx1 = -INFINITY, mx2 = -INFINITY, mx3 = -INFINITY;

#define ACC(v)                                                      \
        sa0 += (v).x; mn0 = fminf(mn0, (v).x); mx0 = fmaxf(mx0, (v).x); \
        sa1 += (v).y; mn1 = fminf(mn1, (v).y); mx1 = fmaxf(mx1, (v).y); \
        sa2 += (v).z; mn2 = fminf(mn2, (v).z); mx2 = fmaxf(mx2, (v).z); \
        sa3 += (v).w; mn3 = fminf(mn3, (v).w); mx3 = fmaxf(mx3, (v).w);

        int j = s0;
        for (; j + 4 <= e0; j += 4) {
            int ea = seid[j], eb = seid[j + 1], ec = seid[j + 2], ed = seid[j + 3];
            float4 va = *(const float4*)&m[ea * D_FEAT + (fo << 2)];
            float4 vb = *(const float4*)&m[eb * D_FEAT + (fo << 2)];
            float4 vc = *(const float4*)&m[ec * D_FEAT + (fo << 2)];
            float4 vd = *(const float4*)&m[ed * D_FEAT + (fo << 2)];
            ACC(va); ACC(vb); ACC(vc); ACC(vd);
        }
        for (; j < e0; j++) {
            float4 v = *(const float4*)&m[seid[j] * D_FEAT + (fo << 2)];
            ACC(v);
        }
#undef ACC

        bool has = deg > 0;
        float inv = 1.0f / fmaxf((float)deg, 1.0f);
        float4 o;
        o.x = w0 * sa0 + w1 * (has ? mn0 : 0.f) + w2 * (has ? mx0 : 0.f) + w3 * (sa0 * inv) + bb;
        o.y = w0 * sa1 + w1 * (has ? mn1 : 0.f) + w2 * (has ? mx1 : 0.f) + w3 * (sa1 * inv) + bb;
        o.z = w0 * sa2 + w1 * (has ? mn2 : 0.f) + w2 * (has ? mx2 : 0.f) + w3 * (sa2 * inv) + bb;
        o.w = w0 * sa3 + w1 * (has ? mn3 : 0.f) + w2 * (has ? mx3 : 0.f) + w3 * (sa3 * inv) + bb;
        *(float4*)&out[node * D_FEAT + (fo << 2)] = o;
    }
}

extern "C" void kernel_launch(void* const* d_in, const int* in_sizes, int n_in,
                              void* d_out, int out_size, void* d_ws, size_t ws_size,
                              hipStream_t stream) {
    const float* m   = (const float*)d_in[0];
    const int*   dst = (const int*)  d_in[1];
    const float* w   = (const float*)d_in[2];
    const float* b   = (const float*)d_in[3];

    int E = in_sizes[0] / D_FEAT;           // 1,600,000 (divisible by 4)
    int N = out_size    / D_FEAT;           // 50,000
    int E4 = E / 4;
    int nbucket = (N + NPB - 1) >> BSHIFT;  // 391
    int nTiles = (E + TILE - 1) / TILE;     // 196

    int* ws         = (int*)d_ws;
    int* tileCnt    = ws;                               // nTiles * MAXBKT
    int* tileBase   = tileCnt  + nTiles * MAXBKT;       // nTiles * MAXBKT
    int* bucketBase = tileBase + nTiles * MAXBKT;       // MAXBKT + 1
    unsigned int* keys = (unsigned int*)(bucketBase + MAXBKT + 1);   // E

    // 4 dispatches, no memset, no device atomics anywhere.
    hipLaunchKernelGGL(hist_kernel, dim3(nTiles), dim3(256), 0, stream,
                       dst, tileCnt, E4);
    hipLaunchKernelGGL(scan_kernel, dim3(1), dim3(512), 0, stream,
                       tileCnt, tileBase, bucketBase, nTiles);
    hipLaunchKernelGGL(partition_kernel, dim3(nTiles), dim3(256), 0, stream,
                       dst, tileCnt, tileBase, keys, E4, nbucket);
    hipLaunchKernelGGL(bucket_gather_kernel, dim3(nbucket), dim3(GBLK), 0, stream,
                       m, keys, bucketBase, w, b, (float*)d_out, N);
}